// Round 1
// baseline (1521.160 us; speedup 1.0000x reference)
//
#include <hip/hip_runtime.h>
#include <math.h>

#define MDIM 4096
#define NDIM 4096
#define DDIM 256
#define N_ITER 30
constexpr float EPSF = 1e-16f;

// ---------- norms: xx[i]=||x_i||^2, yy[j]=||y_j||^2, Sxx = sum_i xx[i] ----------
__global__ void norms_kernel(const float* __restrict__ x, const float* __restrict__ y,
                             float* __restrict__ xx, float* __restrict__ yy,
                             float* __restrict__ Sxx) {
  int wid = threadIdx.x >> 6, lane = threadIdx.x & 63;
  int row = blockIdx.x * 4 + wid;            // 0..8191
  const float* src = (row < MDIM) ? x : y;
  int r = (row < MDIM) ? row : row - MDIM;
  const float4* p = (const float4*)(src + (size_t)r * DDIM);
  float4 v = p[lane];                         // DDIM/4 == 64 → one float4 per lane
  float s = v.x*v.x + v.y*v.y + v.z*v.z + v.w*v.w;
  #pragma unroll
  for (int off = 32; off; off >>= 1) s += __shfl_down(s, off);
  if (lane == 0) {
    if (row < MDIM) { xx[r] = s; atomicAdd(Sxx, s); }
    else            { yy[r] = s; }
  }
}

// ---------- sx[k] = sum_i x[i,k] ----------
__global__ void sx_kernel(const float* __restrict__ x, float* __restrict__ sx) {
  int tx = threadIdx.x;                      // 0..255
  int r0 = blockIdx.x * 16;
  float s = 0.f;
  #pragma unroll
  for (int r = 0; r < 16; ++r) s += x[(size_t)(r0 + r) * DDIM + tx];
  atomicAdd(&sx[tx], s);
}

// ---------- colM[j] = Sxx + MDIM*yy[j] - 2*dot(sx, y_j) ----------
__global__ void colM_kernel(const float* __restrict__ y, const float* __restrict__ sx,
                            const float* __restrict__ yy, const float* __restrict__ Sxx,
                            float* __restrict__ colM) {
  int wid = threadIdx.x >> 6, lane = threadIdx.x & 63;
  int j = blockIdx.x * 4 + wid;
  const float4* py = (const float4*)(y + (size_t)j * DDIM);
  const float4* ps = (const float4*)sx;
  float4 a = py[lane], b = ps[lane];
  float s = a.x*b.x + a.y*b.y + a.z*b.z + a.w*b.w;
  #pragma unroll
  for (int off = 32; off; off >>= 1) s += __shfl_down(s, off);
  if (lane == 0) colM[j] = *Sxx + (float)MDIM * yy[j] - 2.f * s;
}

// ---------- GEMM: K[i,j] = exp(-5*(xx_i + yy_j - 2*x_i.y_j)) / 4096 ----------
#define BMT 128
#define BNT 128
#define BKT 32
__global__ __launch_bounds__(256)
void gemm_k_kernel(const float* __restrict__ x, const float* __restrict__ y,
                   const float* __restrict__ xx, const float* __restrict__ yy,
                   float* __restrict__ Kmat) {
  __shared__ float As[BMT][BKT + 1];
  __shared__ float Bs[BNT][BKT + 1];
  int tid = threadIdx.x;
  int bm = blockIdx.x & 31, bn = blockIdx.x >> 5;
  int tx = tid & 15, ty = tid >> 4;
  float acc[8][8] = {};
  for (int k0 = 0; k0 < DDIM; k0 += BKT) {
    #pragma unroll
    for (int q = 0; q < 4; ++q) {
      int li = tid + 256 * q;                // 0..1023
      int row = li >> 3, ks = (li & 7) * 4;
      float4 v = *(const float4*)(x + (size_t)(bm * BMT + row) * DDIM + k0 + ks);
      As[row][ks+0] = v.x; As[row][ks+1] = v.y; As[row][ks+2] = v.z; As[row][ks+3] = v.w;
    }
    #pragma unroll
    for (int q = 0; q < 4; ++q) {
      int li = tid + 256 * q;
      int row = li >> 3, ks = (li & 7) * 4;
      float4 v = *(const float4*)(y + (size_t)(bn * BNT + row) * DDIM + k0 + ks);
      Bs[row][ks+0] = v.x; Bs[row][ks+1] = v.y; Bs[row][ks+2] = v.z; Bs[row][ks+3] = v.w;
    }
    __syncthreads();
    #pragma unroll
    for (int kk = 0; kk < BKT; ++kk) {
      float a[8], b[8];
      #pragma unroll
      for (int r = 0; r < 8; ++r) a[r] = As[ty*8 + r][kk];
      #pragma unroll
      for (int c = 0; c < 8; ++c) b[c] = Bs[tx*8 + c][kk];
      #pragma unroll
      for (int r = 0; r < 8; ++r)
        #pragma unroll
        for (int c = 0; c < 8; ++c) acc[r][c] += a[r] * b[c];
    }
    __syncthreads();
  }
  float xr[8], yc[8];
  #pragma unroll
  for (int r = 0; r < 8; ++r) xr[r] = xx[bm*BMT + ty*8 + r];
  #pragma unroll
  for (int c = 0; c < 8; ++c) yc[c] = yy[bn*BNT + tx*8 + c];
  #pragma unroll
  for (int r = 0; r < 8; ++r) {
    int gi = bm*BMT + ty*8 + r;
    float ov[8];
    #pragma unroll
    for (int c = 0; c < 8; ++c) {
      float Mv = xr[r] + yc[c] - 2.f * acc[r][c];
      ov[c] = __expf(-5.f * Mv) * (1.f / 4096.f);
    }
    float* dst = Kmat + (size_t)gi * NDIM + bn*BNT + tx*8;
    *(float4*)dst       = make_float4(ov[0], ov[1], ov[2], ov[3]);
    *(float4*)(dst + 4) = make_float4(ov[4], ov[5], ov[6], ov[7]);
  }
}

// ---------- one MM step: G_new = K*G / (sqrt(r_i)*sqrt(c_j)+eps); accumulate new r,c ----------
#define SROWS 32
#define SCOLS 1024
template<bool FIRST>
__global__ __launch_bounds__(256)
void step_kernel(const float* __restrict__ Kmat, float* __restrict__ G,
                 const float* __restrict__ r_in, const float* __restrict__ c_in,
                 float* __restrict__ r_out, float* __restrict__ c_out,
                 float s1) {
  __shared__ float rp[SROWS][4];
  int tid = threadIdx.x;
  int wid = tid >> 6, lane = tid & 63;
  int cb = blockIdx.x & 3;                   // NDIM/SCOLS = 4
  int rb = blockIdx.x >> 2;
  int row0 = rb * SROWS;
  int col = cb * SCOLS + tid * 4;
  float sc[4], csum[4] = {0.f, 0.f, 0.f, 0.f};
  if (!FIRST) {
    float4 cv = *(const float4*)(c_in + col);
    sc[0] = sqrtf(cv.x); sc[1] = sqrtf(cv.y); sc[2] = sqrtf(cv.z); sc[3] = sqrtf(cv.w);
  }
  for (int r = 0; r < SROWS; ++r) {
    size_t base = (size_t)(row0 + r) * NDIM + col;
    float4 kv = *(const float4*)(Kmat + base);
    float g0, g1, g2, g3;
    if (FIRST) {
      g0 = kv.x * s1; g1 = kv.y * s1; g2 = kv.z * s1; g3 = kv.w * s1;
    } else {
      float4 gv = *(const float4*)(G + base);
      float sr = sqrtf(r_in[row0 + r]);
      g0 = __fdividef(kv.x * gv.x, sr * sc[0] + EPSF);
      g1 = __fdividef(kv.y * gv.y, sr * sc[1] + EPSF);
      g2 = __fdividef(kv.z * gv.z, sr * sc[2] + EPSF);
      g3 = __fdividef(kv.w * gv.w, sr * sc[3] + EPSF);
    }
    *(float4*)(G + base) = make_float4(g0, g1, g2, g3);
    csum[0] += g0; csum[1] += g1; csum[2] += g2; csum[3] += g3;
    float rsum = g0 + g1 + g2 + g3;
    #pragma unroll
    for (int off = 32; off; off >>= 1) rsum += __shfl_down(rsum, off);
    if (lane == 0) rp[r][wid] = rsum;
  }
  __syncthreads();
  if (tid < SROWS) {
    float s = rp[tid][0] + rp[tid][1] + rp[tid][2] + rp[tid][3];
    atomicAdd(&r_out[row0 + tid], s);
  }
  #pragma unroll
  for (int q = 0; q < 4; ++q) atomicAdd(&c_out[col + q], csum[q]);
}

// ---------- loss = dot(c_final, colM) / m^2 ----------
__global__ void loss_kernel(const float* __restrict__ c_fin, const float* __restrict__ colM,
                            float* __restrict__ out) {
  __shared__ float sp[4];
  int tid = threadIdx.x, wid = tid >> 6, lane = tid & 63;
  float s = 0.f;
  for (int j = tid; j < NDIM; j += 256) s += c_fin[j] * colM[j];
  #pragma unroll
  for (int off = 32; off; off >>= 1) s += __shfl_down(s, off);
  if (lane == 0) sp[wid] = s;
  __syncthreads();
  if (tid == 0) out[0] = (sp[0] + sp[1] + sp[2] + sp[3]) * (1.f / ((float)MDIM * (float)MDIM));
}

extern "C" void kernel_launch(void* const* d_in, const int* in_sizes, int n_in,
                              void* d_out, int out_size, void* d_ws, size_t ws_size,
                              hipStream_t stream) {
  const float* x = (const float*)d_in[0];
  const float* y = (const float*)d_in[1];
  float* out = (float*)d_out;

  char* ws = (char*)d_ws;
  size_t off = 0;
  auto alloc = [&](size_t bytes) -> void* {
    void* p = ws + off;
    off += (bytes + 255) & ~(size_t)255;
    return p;
  };
  float* Kmat = (float*)alloc((size_t)MDIM * NDIM * 4);   // 64 MB
  float* G    = (float*)alloc((size_t)MDIM * NDIM * 4);   // 64 MB
  float* xx   = (float*)alloc(MDIM * 4);
  float* yy   = (float*)alloc(NDIM * 4);
  float* sx   = (float*)alloc(DDIM * 4);
  float* colM = (float*)alloc(NDIM * 4);
  float* Sxx  = (float*)alloc(4);
  float* rbuf[2], *cbuf[2];
  rbuf[0] = (float*)alloc(MDIM * 4); rbuf[1] = (float*)alloc(MDIM * 4);
  cbuf[0] = (float*)alloc(NDIM * 4); cbuf[1] = (float*)alloc(NDIM * 4);

  hipMemsetAsync(Sxx, 0, 4, stream);
  hipMemsetAsync(sx, 0, DDIM * 4, stream);
  norms_kernel<<<2048, 256, 0, stream>>>(x, y, xx, yy, Sxx);
  sx_kernel<<<256, 256, 0, stream>>>(x, sx);
  colM_kernel<<<1024, 256, 0, stream>>>(y, sx, yy, Sxx, colM);
  gemm_k_kernel<<<1024, 256, 0, stream>>>(x, y, xx, yy, Kmat);

  // step 1: G0 = a b^T is uniform → G1 = K * s1 with a scalar
  double d0 = 1.0 / 4096.0 + 1e-16;
  float s1 = (float)((1.0 / ((double)MDIM * (double)NDIM)) / d0);

  hipMemsetAsync(rbuf[0], 0, MDIM * 4, stream);
  hipMemsetAsync(cbuf[0], 0, NDIM * 4, stream);
  step_kernel<true><<<512, 256, 0, stream>>>(Kmat, G, nullptr, nullptr,
                                             rbuf[0], cbuf[0], s1);
  for (int t = 2; t <= N_ITER; ++t) {
    int q = (t - 1) & 1;
    hipMemsetAsync(rbuf[q], 0, MDIM * 4, stream);
    hipMemsetAsync(cbuf[q], 0, NDIM * 4, stream);
    step_kernel<false><<<512, 256, 0, stream>>>(Kmat, G, rbuf[1 - q], cbuf[1 - q],
                                                rbuf[q], cbuf[q], 0.f);
  }
  loss_kernel<<<1, 256, 0, stream>>>(cbuf[(N_ITER - 1) & 1], colM, out);
}